// Round 3
// baseline (526.226 us; speedup 1.0000x reference)
//
#include <hip/hip_runtime.h>

#define BM 64
#define BK 64
#define NE 64
#define TAU 3e-4f
#define LSTR 67  // padded stride for epilogue score transpose (67 mod 32 = 3)

// async global->LDS, 16B per lane; LDS dest = wave-uniform base + lane*16
__device__ __forceinline__ void gld16(const float* g, float* l) {
  __builtin_amdgcn_global_load_lds(
      (const __attribute__((address_space(1))) void*)g,
      (__attribute__((address_space(3))) void*)l, 16, 0, 0);
}

// Fused: gate GEMM (f32, swizzled LDS, double-buffered gload_lds) + softmax
// + top-9 + near-tie deferral + histogram, all per 64-token block.
// Swizzle: logical quad q of row r lives at phys quad q ^ swz(r),
// swz(r) = (r&7) ^ ((r>>2)&3). A-reads (rows 16w+4g+i) hit 4 distinct
// bank-groups; B-reads (rows tcl+16j) are 2-way (free).
__global__ __launch_bounds__(256, 2) void gemm_fused(
    const float* __restrict__ X, const float* __restrict__ W,
    const float* __restrict__ bias, float* __restrict__ S,
    float* __restrict__ wout, float* __restrict__ iout,
    int* __restrict__ cnt, int* __restrict__ hist, int* __restrict__ list,
    int cap, int H, int K) {
  __shared__ float As[2][BM * BK];
  __shared__ float Bs[2][NE * BK];
  __shared__ int hist_s[NE];
  const int tid = threadIdx.x;
  const int lane = tid & 63;
  const int wave = tid >> 6;
  const int row0 = blockIdx.x * BM;
  if (tid < NE) hist_s[tid] = 0;

  // ---- staging source pointers (pre-swizzled global addresses) ----
  const int lrow = lane >> 4;  // 0..3: row within 4-row group
  const int c4 = lane & 15;    // phys quad this lane fills
  const float* asrc[4];
  const float* bsrc[4];
#pragma unroll
  for (int o = 0; o < 4; ++o) {
    const int r = 16 * wave + 4 * o + lrow;
    const int swz = (r & 7) ^ ((r >> 2) & 3);
    const int sc4 = c4 ^ swz;  // logical quad that phys quad c4 must hold
    asrc[o] = X + (size_t)(row0 + r) * H + sc4 * 4;
    bsrc[o] = W + (size_t)r * H + sc4 * 4;
  }

#define ISSUE(t, buf)                                                       \
  do {                                                                      \
    const int kk_ = (t)*BK;                                                 \
    _Pragma("unroll") for (int o = 0; o < 4; ++o) {                         \
      gld16(asrc[o] + kk_, &As[buf][(16 * wave + 4 * o) * BK]);             \
      gld16(bsrc[o] + kk_, &Bs[buf][(16 * wave + 4 * o) * BK]);             \
    }                                                                       \
  } while (0)

  // ---- compute-side indices ----
  const int tcl = tid & 15;       // expert lane group: experts tcl+16j
  const int tr = (tid >> 4) * 4;  // 4 tokens per thread
  const int swzB = (tcl & 7) ^ ((tcl >> 2) & 3);
  int swzA[4];
#pragma unroll
  for (int i = 0; i < 4; ++i)
    swzA[i] = ((tr + i) & 7) ^ (((tr + i) >> 2) & 3);

  float acc[4][4] = {};
  const int T = H / BK;

  ISSUE(0, 0);
  for (int t = 0; t < T; ++t) {
    const int buf = t & 1;
    if (t + 1 < T) {
      ISSUE(t + 1, buf ^ 1);
      asm volatile("s_waitcnt vmcnt(8)" ::: "memory");  // tile t landed
    } else {
      asm volatile("s_waitcnt vmcnt(0)" ::: "memory");
    }
    __builtin_amdgcn_s_barrier();
    asm volatile("" ::: "memory");
    float acc_t[4][4] = {};  // per-tile sub-accumulator (pairwise summation)
#pragma unroll
    for (int q = 0; q < BK / 4; ++q) {
      float4 b4[4];
      const int qb = ((q ^ swzB) << 2);
#pragma unroll
      for (int j = 0; j < 4; ++j)
        b4[j] = *reinterpret_cast<const float4*>(
            &Bs[buf][(tcl + 16 * j) * BK + qb]);
#pragma unroll
      for (int i = 0; i < 4; ++i) {
        const float4 a4 = *reinterpret_cast<const float4*>(
            &As[buf][(tr + i) * BK + ((q ^ swzA[i]) << 2)]);
#pragma unroll
        for (int j = 0; j < 4; ++j) {
          acc_t[i][j] = fmaf(a4.x, b4[j].x, acc_t[i][j]);
          acc_t[i][j] = fmaf(a4.y, b4[j].y, acc_t[i][j]);
          acc_t[i][j] = fmaf(a4.z, b4[j].z, acc_t[i][j]);
          acc_t[i][j] = fmaf(a4.w, b4[j].w, acc_t[i][j]);
        }
      }
    }
#pragma unroll
    for (int i = 0; i < 4; ++i)
#pragma unroll
      for (int j = 0; j < 4; ++j) acc[i][j] += acc_t[i][j];
    asm volatile("" ::: "memory");
    __builtin_amdgcn_s_barrier();
    asm volatile("" ::: "memory");
  }
#undef ISSUE

  // ---- epilogue: transpose scores via padded LDS, then per-wave softmax ----
  float* Ls = &As[0][0];  // 64*67 = 4288 floats <= 8192
#pragma unroll
  for (int i = 0; i < 4; ++i)
#pragma unroll
    for (int j = 0; j < 4; ++j)
      Ls[(tr + i) * LSTR + tcl + 16 * j] = acc[i][j];
  __syncthreads();

  const float bv = bias[lane];
  for (int tt = 0; tt < 16; ++tt) {
    const int tl = wave * 16 + tt;
    const int t = row0 + tl;
    const float s = Ls[tl * LSTR + lane] + bv;

    float m = s;
#pragma unroll
    for (int off = 32; off >= 1; off >>= 1) m = fmaxf(m, __shfl_xor(m, off));
    const float e = expf(s - m);
    float sum = e;
#pragma unroll
    for (int off = 32; off >= 1; off >>= 1) sum += __shfl_xor(sum, off);
    const float p = e / sum;

    // top-9 on biased raw score, lowest-index tie-break (matches lax.top_k)
    float wsel = s;
    float rv = 0.f;
    int ri = 0;
    float prev = 0.f, mingap = 1e30f;
#pragma unroll
    for (int r = 0; r < 9; ++r) {
      float v = wsel;
      int ii = lane;
#pragma unroll
      for (int off = 32; off >= 1; off >>= 1) {
        const float ov = __shfl_xor(v, off);
        const int oi = __shfl_xor(ii, off);
        if (ov > v || (ov == v && oi < ii)) { v = ov; ii = oi; }
      }
      if (r > 0) mingap = fminf(mingap, prev - v);
      prev = v;
      const float pw = __shfl(p, ii);
      if (lane == r) { rv = pw; ri = ii; }
      if (lane == ii) wsel = -1e30f;
    }

    bool toC = false;
    if (mingap < TAU && cap > 0) {
      int pos = 0;
      if (lane == 0) pos = atomicAdd(cnt, 1);
      pos = __shfl(pos, 0);
      if (pos < cap) {
        if (lane == 0) list[pos] = t;
        toC = true;  // recompute kernel produces all outputs for this token
      }
    }
    if (!toC) {
      S[(size_t)t * NE + lane] = p;
      if (lane < K) {
        wout[(size_t)t * K + lane] = rv;
        iout[(size_t)t * K + lane] = (float)ri;
        atomicAdd(&hist_s[ri], 1);
      }
    }
  }
  __syncthreads();
  if (tid < NE) atomicAdd(&hist[tid], hist_s[tid]);
}

// ------------- f64 recompute for flagged (near-tie) tokens --------
__global__ __launch_bounds__(256) void recompute_f64(
    const float* __restrict__ X, const float* __restrict__ W,
    const float* __restrict__ bias, float* __restrict__ S,
    float* __restrict__ wout, float* __restrict__ iout,
    const int* __restrict__ cnt, const int* __restrict__ list,
    int* __restrict__ hist, int H, int K, int cap) {
  if (cap <= 0) return;
  __shared__ float xs[4096];
  __shared__ double red[256];
  const int tid = threadIdx.x;
  const int n = min(*cnt, cap);
  for (int idx = blockIdx.x; idx < n; idx += gridDim.x) {
    const int t = list[idx];
    for (int i = tid; i < H / 4; i += 256)
      reinterpret_cast<float4*>(xs)[i] =
          reinterpret_cast<const float4*>(X + (size_t)t * H)[i];
    __syncthreads();
    const int e = tid & 63, sl = tid >> 6;
    const float* wr = W + (size_t)e * H + sl * (H / 4);
    const float* xr = xs + sl * (H / 4);
    double acc = 0.0;
    for (int k = 0; k < H / 4; k += 4) {
      const float4 wv = *reinterpret_cast<const float4*>(wr + k);
      const float4 xv = *reinterpret_cast<const float4*>(xr + k);
      acc = fma((double)xv.x, (double)wv.x, acc);
      acc = fma((double)xv.y, (double)wv.y, acc);
      acc = fma((double)xv.z, (double)wv.z, acc);
      acc = fma((double)xv.w, (double)wv.w, acc);
    }
    red[tid] = acc;
    __syncthreads();
    if (tid < 64) {
      double s =
          red[e] + red[64 + e] + red[128 + e] + red[192 + e] + (double)bias[e];
      double m = s;
#pragma unroll
      for (int off = 32; off >= 1; off >>= 1) m = fmax(m, __shfl_xor(m, off));
      const double ex = exp(s - m);
      double sum = ex;
#pragma unroll
      for (int off = 32; off >= 1; off >>= 1) sum += __shfl_xor(sum, off);
      const double p = ex / sum;
      S[(size_t)t * NE + e] = (float)p;
      double wsel = s;
      double rv = 0.0;
      int ri = 0;
      for (int r = 0; r < K; ++r) {
        double v = wsel;
        int ii = e;
#pragma unroll
        for (int off = 32; off >= 1; off >>= 1) {
          const double ov = __shfl_xor(v, off);
          const int oi = __shfl_xor(ii, off);
          if (ov > v || (ov == v && oi < ii)) { v = ov; ii = oi; }
        }
        const double pw = __shfl(p, ii);
        if (e == r) { rv = pw; ri = ii; }
        if (e == ii) wsel = -1e300;
      }
      if (e < K) {
        wout[(size_t)t * K + e] = (float)rv;
        iout[(size_t)t * K + e] = (float)ri;
        atomicAdd(&hist[ri], 1);
      }
    }
    __syncthreads();
  }
}

// ------------- bias update from integer histogram -----------------
__global__ void bias_update(const int* __restrict__ hist,
                            const float* __restrict__ bias,
                            float* __restrict__ bout, float tpe) {
  const int e = threadIdx.x;
  const float d = (float)hist[e] - tpe;
  const float sg = (d > 0.f) ? 1.f : ((d < 0.f) ? -1.f : 0.f);
  bout[e] = bias[e] + 0.01f * sg;
}

extern "C" void kernel_launch(void* const* d_in, const int* in_sizes, int n_in,
                              void* d_out, int out_size, void* d_ws, size_t ws_size,
                              hipStream_t stream) {
  const float* x = (const float*)d_in[0];
  const float* w = (const float*)d_in[1];
  const float* bias = (const float*)d_in[2];
  const int E = in_sizes[2];                       // 64
  const int H = in_sizes[1] / E;                   // 4096
  const long long N = (long long)in_sizes[0] / H;  // 32768 tokens
  const int K = (int)(((long long)out_size - N * E - E) / (2 * N));  // 8

  float* S = (float*)d_out;            // [N][E] probs
  float* wout = S + (size_t)N * E;     // [N][K]
  float* iout = wout + (size_t)N * K;  // [N][K] indices as float
  float* bout = iout + (size_t)N * K;  // [E]

  // workspace: [0,4) count | [256,512) int hist | [1024,...) token list
  int* cnt = (int*)d_ws;
  int* hist = (int*)d_ws + 64;
  int* list = (int*)d_ws + 256;
  int cap = 0;
  if (ws_size >= 4096) cap = (int)min((size_t)131072, (ws_size - 1024) / 4);
  if (ws_size >= 512) hipMemsetAsync(d_ws, 0, 512, stream);

  gemm_fused<<<dim3((int)(N / BM)), 256, 0, stream>>>(
      x, w, bias, S, wout, iout, cnt, hist, list, cap, H, K);
  recompute_f64<<<dim3(256), 256, 0, stream>>>(x, w, bias, S, wout, iout, cnt,
                                               list, hist, H, K, cap);
  bias_update<<<dim3(1), dim3(E), 0, stream>>>(hist, bias, bout,
                                               (float)((double)N * K / E));
}